// Round 1
// baseline (159.886 us; speedup 1.0000x reference)
//
#include <hip/hip_runtime.h>
#include <hip/hip_bf16.h>
#include <cstdint>
#include <cstddef>

// SetConvDecoder on MI355X.
// out[b,t,c] = (1/128) * sum_g exp(-0.5*||(xt[b,t]-xg[b,g])/ls||^2) * zg[b,g,c]
// B=4, NT=2048, NG=16384, DZ=128, DX=2.
//
// Strategy: bf16 MFMA (32x32x16) GEMM with the A-matrix (RBF weights)
// generated in registers. exp(-0.5 d2) == exp2(2ut.ug - |ut|^2 - |ug|^2)
// with u = x * sqrt(0.5*log2 e)/ls  -> 3 VALU + 1 v_exp_f32 per weight.
//
// ws layout (needs ~33.7 MB):
//   [0, 16MB)      zg in bf16, pre-permuted per K-tile into fragment order
//   [16MB, +768K)  xg triplets (2u0, 2u1, -|ug|^2) grouped per K-tile
//   [.., +96K)     xt triplets (u0, u1, -|ut|^2)
//   [.., +16MB)    fp32 partials, one 128x128 tile per (ksplit,b,mtile)

typedef float  f32x4  __attribute__((ext_vector_type(4)));
typedef float  f32x16 __attribute__((ext_vector_type(16)));
typedef short  short8 __attribute__((ext_vector_type(8)));
typedef unsigned short ushort8 __attribute__((ext_vector_type(8)));

#if __has_builtin(__builtin_amdgcn_exp2f)
#define EXP2F(x) __builtin_amdgcn_exp2f(x)
#else
#define EXP2F(x) exp2f(x)
#endif

#define AS1C(p) ((const __attribute__((address_space(1))) void*)(p))
#define AS3(p)  ((__attribute__((address_space(3))) void*)(p))

__device__ __forceinline__ unsigned short bf16_bits(float f) {
  __bf16 h = (__bf16)f;  // RTNE; compiler pairs these into v_cvt_pk_bf16_f32
  return __builtin_bit_cast(unsigned short, h);
}

// ---------------------------------------------------------------------------
// Pre-kernel: zg fp32 -> bf16 permuted; xg/xt scaled triplets.
// Per K-tile (32 k's) layout, bf16 element index inside the 4096-elem tile:
//   addr = (h*256 + q2*128 + c)*8 + hi*4 + j   with k = 16h + 4q2 + 8hi + j
// so a lane's B-fragment (n = l&31 ... c, q2 = l>>5) is one contiguous 16B.
// ---------------------------------------------------------------------------
__global__ __launch_bounds__(256) void pre_kernel(
    const float* __restrict__ x_grid, const float* __restrict__ z_grid,
    const float* __restrict__ xt, const float* __restrict__ lsp,
    unsigned short* __restrict__ zgb, float* __restrict__ xg_trip,
    float* __restrict__ xt_trip)
{
  const int bid = blockIdx.x;         // 0..2047 = b*512 + t
  const int b   = bid >> 9;
  const int t   = bid & 511;
  const int tid = threadIdx.x;

  const size_t zbase = (size_t)b * 16384 * 128;
  unsigned short* dst_tile = zgb + ((size_t)(b * 512 + t)) * 4096;

  #pragma unroll
  for (int it = 0; it < 2; ++it) {
    const int o8 = it * 256 + tid;    // 0..511 : one 16B group each
    const int h  = o8 >> 8;
    const int q2 = (o8 >> 7) & 1;
    const int c  = o8 & 127;
    const int kb = t * 32 + h * 16 + q2 * 4;
    ushort8 v;
    #pragma unroll
    for (int hi = 0; hi < 2; ++hi)
      #pragma unroll
      for (int j = 0; j < 4; ++j) {
        float f = z_grid[zbase + (size_t)(kb + 8 * hi + j) * 128 + c];
        v[hi * 4 + j] = bf16_bits(f);
      }
    *(ushort8*)(dst_tile + o8 * 8) = v;
  }

  if (tid < 64) {
    const float ls0 = 1e-5f + log1pf(expf(lsp[0]));
    const float ls1 = 1e-5f + log1pf(expf(lsp[1]));
    const float cs  = sqrtf(0.7213475204444817f);  // sqrt(0.5*log2(e))
    const float s0 = cs / ls0, s1 = cs / ls1;
    if (tid < 32) {
      const int g = t * 32 + tid;
      const float u0 = x_grid[(size_t)(b * 16384 + g) * 2 + 0] * s0;
      const float u1 = x_grid[(size_t)(b * 16384 + g) * 2 + 1] * s1;
      float* d = xg_trip + (size_t)(b * 512 + t) * 96 + tid * 3;
      d[0] = 2.0f * u0; d[1] = 2.0f * u1; d[2] = -(u0 * u0 + u1 * u1);
    } else if (t < 64) {
      const int r = t * 32 + (tid - 32);
      const float u0 = xt[(size_t)(b * 2048 + r) * 2 + 0] * s0;
      const float u1 = xt[(size_t)(b * 2048 + r) * 2 + 1] * s1;
      float* d = xt_trip + (size_t)(b * 2048 + r) * 3;
      d[0] = u0; d[1] = u1; d[2] = -(u0 * u0 + u1 * u1);
    }
  }
}

// ---------------------------------------------------------------------------
// Main kernel: 256 blocks = (b:4, mtile:16, ksplit:4), 512 threads = 8 waves.
// Wave wv: rh = wv&1 (row half, 64 rows), kp = wv>>1 (K parity).
// Wave kp handles 16-k sub-steps s where s%4==kp -> per 32-k tile, parities
// {2*(t%2), 2*(t%2)+1} are active; wv and wv+4 (same SIMD under round-robin)
// have complementary parity so each SIMD has one MFMA-active wave per tile.
// acc: 2 mtiles x 4 ntiles x f32x16 = 128 VGPR.
// ---------------------------------------------------------------------------
__global__ __launch_bounds__(512, 2) void main_kernel(
    const unsigned short* __restrict__ zgb,
    const float* __restrict__ xg_trip,
    const float* __restrict__ xt_trip,
    float* __restrict__ partials)
{
  __shared__ __align__(128) char smem[24576];
  char*  zbuf  = smem;                      // [2][8192] staged zg tiles
  float* xgbuf = (float*)(smem + 16384);    // [2][96]   staged xg triplets

  const int bid = blockIdx.x;
  const int ks  = bid & 3;
  const int mt  = (bid >> 2) & 15;
  const int b   = bid >> 6;

  const int tid = threadIdx.x;
  const int wv  = tid >> 6;
  const int l   = tid & 63;
  const int rh  = wv & 1;
  const int kp  = wv >> 1;
  const int h   = kp & 1;       // which 16-k half of a staged 32-k tile
  const int tp  = kp >> 1;      // which tile parity
  const int l31 = l & 31;
  const int q2  = l >> 5;       // k-group within fragment

  // per-lane xt triplets for this wave's 2 row-tiles
  float at0[2], at1[2], ca[2];
  #pragma unroll
  for (int mi = 0; mi < 2; ++mi) {
    const int r = mt * 128 + rh * 64 + mi * 32 + l31;
    const float* p = xt_trip + (size_t)(b * 2048 + r) * 3;
    at0[mi] = p[0]; at1[mi] = p[1]; ca[mi] = p[2];
  }

  f32x16 acc[2][4];
  #pragma unroll
  for (int mi = 0; mi < 2; ++mi)
    #pragma unroll
    for (int ni = 0; ni < 4; ++ni)
      #pragma unroll
      for (int e = 0; e < 16; ++e)
        acc[mi][ni][e] = 0.0f;

  const size_t tilebase = (size_t)(b * 512 + ks * 128);
  const char*  zsrc = (const char*)zgb + tilebase * 8192;
  const char*  xsrc = (const char*)(xg_trip) + tilebase * 384;

  auto stage = [&](int t, int bb) {
    __builtin_amdgcn_global_load_lds(
        AS1C(zsrc + (size_t)t * 8192 + wv * 1024 + l * 16),
        AS3(zbuf + bb * 8192 + wv * 1024 + l * 16), 16, 0, 0);
    if (l < 3) {
      __builtin_amdgcn_global_load_lds(
          AS1C(xsrc + (size_t)t * 384 + wv * 48 + l * 16),
          AS3((char*)xgbuf + bb * 384 + wv * 48 + l * 16), 16, 0, 0);
    }
  };

  stage(0, 0);

  for (int t = 0; t < 128; ++t) {
    __syncthreads();                    // drains stage(t); buf t&1 ready
    if (t + 1 < 128) stage(t + 1, (t + 1) & 1);  // prefetch overlaps compute
    if ((t & 1) == tp) {
      const int bb = t & 1;

      // xg triplets for this lane's 8 k's: k16 = 4*q2 + j (+8 for high half)
      const f32x4* xq = (const f32x4*)(xgbuf + bb * 96 + (h * 16 + q2 * 4) * 3);
      const f32x4 A0 = xq[0], A1 = xq[1], A2 = xq[2];
      const f32x4 B0 = xq[6], B1 = xq[7], B2 = xq[8];
      float g0[8], g1[8], cb[8];
      g0[0]=A0.x; g1[0]=A0.y; cb[0]=A0.z;
      g0[1]=A0.w; g1[1]=A1.x; cb[1]=A1.y;
      g0[2]=A1.z; g1[2]=A1.w; cb[2]=A2.x;
      g0[3]=A2.y; g1[3]=A2.z; cb[3]=A2.w;
      g0[4]=B0.x; g1[4]=B0.y; cb[4]=B0.z;
      g0[5]=B0.w; g1[5]=B1.x; cb[5]=B1.y;
      g0[6]=B1.z; g1[6]=B1.w; cb[6]=B2.x;
      g0[7]=B2.y; g1[7]=B2.z; cb[7]=B2.w;

      // generate A-fragments (weights) in registers
      short8 af[2];
      #pragma unroll
      for (int mi = 0; mi < 2; ++mi) {
        union { short8 s; __bf16 e[8]; } u;
        #pragma unroll
        for (int j = 0; j < 8; ++j) {
          float arg = __builtin_fmaf(at0[mi], g0[j],
                      __builtin_fmaf(at1[mi], g1[j], ca[mi] + cb[j]));
          u.e[j] = (__bf16)EXP2F(arg);   // = exp(-0.5*dist2) <= 1
        }
        af[mi] = u.s;
      }

      // B-fragments: one ds_read_b128 each, conflict-free layout
      const char* zt = zbuf + bb * 8192 + h * 4096 + (q2 * 128 + l31) * 16;
      short8 bfr[4];
      #pragma unroll
      for (int ni = 0; ni < 4; ++ni)
        bfr[ni] = *(const short8*)(zt + ni * 512);

      #pragma unroll
      for (int mi = 0; mi < 2; ++mi)
        #pragma unroll
        for (int ni = 0; ni < 4; ++ni)
          acc[mi][ni] = __builtin_amdgcn_mfma_f32_32x32x16_bf16(
              af[mi], bfr[ni], acc[mi][ni], 0, 0, 0);
    }
  }

  // ---- in-block reduction over the 4 K-parities (kp=0 accumulates) ----
  __syncthreads();
  float* red = (float*)smem;   // 2*3*64*16 f32 = 24 KB, aliases staging bufs
  float* pb = partials + ((size_t)(ks * 64 + b * 16 + mt)) * 16384;

  #pragma unroll
  for (int mi = 0; mi < 2; ++mi)
    #pragma unroll
    for (int ni = 0; ni < 4; ++ni) {
      if (kp != 0)
        *(f32x16*)(red + ((rh * 3 + (kp - 1)) * 64 + l) * 16) = acc[mi][ni];
      __syncthreads();
      if (kp == 0) {
        f32x16 s = acc[mi][ni];
        #pragma unroll
        for (int src = 0; src < 3; ++src) {
          const f32x4* sp = (const f32x4*)(red + ((rh * 3 + src) * 64 + l) * 16);
          #pragma unroll
          for (int q = 0; q < 4; ++q) {
            f32x4 v = sp[q];
            s[q*4+0] += v.x; s[q*4+1] += v.y; s[q*4+2] += v.z; s[q*4+3] += v.w;
          }
        }
        const int colb = ni * 32 + l31;
        const int rowb = rh * 64 + mi * 32 + 4 * q2;
        #pragma unroll
        for (int r = 0; r < 16; ++r) {
          const int row = rowb + (r & 3) + 8 * (r >> 2);  // verified C/D map
          pb[row * 128 + colb] = s[r];
        }
      }
      __syncthreads();
    }
}

// ---------------------------------------------------------------------------
// Reduce: out = (sum over 4 ksplit partials) / 128
// ---------------------------------------------------------------------------
__global__ __launch_bounds__(256) void reduce_kernel(
    const float* __restrict__ partials, float* __restrict__ out)
{
  const size_t base = ((size_t)blockIdx.x * 256 + threadIdx.x) * 4;
  const int b  = (int)(base >> 18);
  const int mt = (int)(base >> 14) & 15;
  const int rc = (int)(base & 16383);
  const float* p = partials + ((size_t)(b * 16 + mt)) * 16384 + rc;
  f32x4 s = *(const f32x4*)p;
  #pragma unroll
  for (int ksv = 1; ksv < 4; ++ksv) {
    f32x4 v = *(const f32x4*)(p + (size_t)ksv * 64 * 16384);
    s.x += v.x; s.y += v.y; s.z += v.z; s.w += v.w;
  }
  const float inv = 1.0f / 128.0f;
  s.x *= inv; s.y *= inv; s.z *= inv; s.w *= inv;
  *(f32x4*)(out + base) = s;
}

// ---------------------------------------------------------------------------
extern "C" void kernel_launch(void* const* d_in, const int* in_sizes, int n_in,
                              void* d_out, int out_size, void* d_ws, size_t ws_size,
                              hipStream_t stream) {
  const float* x_grid = (const float*)d_in[0];   // (4,128,128,2)
  const float* z_grid = (const float*)d_in[1];   // (4,128,128,128)
  const float* xt     = (const float*)d_in[2];   // (4,2048,2)
  const float* lsp    = (const float*)d_in[3];   // (2,)
  float* out = (float*)d_out;                    // (4,2048,128) f32

  char* ws = (char*)d_ws;                        // needs ~33.7 MB
  unsigned short* zgb = (unsigned short*)ws;                         // 16 MB
  float* xg_trip  = (float*)(ws + 16777216);                         // 768 KB
  float* xt_trip  = (float*)(ws + 16777216 + 786432);                // 96 KB
  float* partials = (float*)(ws + 16777216 + 786432 + 98304);        // 16 MB

  pre_kernel<<<2048, 256, 0, stream>>>(x_grid, z_grid, xt, lsp,
                                       zgb, xg_trip, xt_trip);
  main_kernel<<<256, 512, 0, stream>>>(zgb, xg_trip, xt_trip, partials);
  reduce_kernel<<<1024, 256, 0, stream>>>(partials, out);
}

// Round 2
// 145.443 us; speedup vs baseline: 1.0993x; 1.0993x over previous
//
#include <hip/hip_runtime.h>
#include <hip/hip_bf16.h>
#include <cstdint>
#include <cstddef>

// SetConvDecoder on MI355X (gfx950).
// out[b,t,c] = (1/128) * sum_g exp(-0.5*||(xt[b,t]-xg[b,g])/ls||^2) * zg[b,g,c]
// B=4, NT=2048, NG=16384, DZ=128, DX=2.
//
// Round-2 structure:
//   pre_kernel : zg -> bf16*(1/128), permuted per 16-k tile into MFMA B-frag
//                order; xg/xt scaled triplets (fold softplus + log2e consts).
//   main_kernel: 256 blocks (b4 x mt16 x ks4) x 512 thr. 8 waves =
//                2 row-halves x 4 contiguous K-quarters, ALL active every
//                iteration. 3-deep LDS ring staged via global_load_lds,
//                counted s_waitcnt vmcnt(3) + raw s_barrier (loads in flight
//                across barriers). Weights generated in registers
//                (3 VALU + 1 v_exp per weight), mfma_f32_32x32x16_bf16.
//                In-block ks... K-quarter reduction in conflict-free [q][lane]
//                LDS planes, then fp32 atomicAdd into memset-zeroed out.

typedef float  f32x4  __attribute__((ext_vector_type(4)));
typedef float  f32x16 __attribute__((ext_vector_type(16)));
typedef short  short8 __attribute__((ext_vector_type(8)));
typedef unsigned short ushort8 __attribute__((ext_vector_type(8)));

#if __has_builtin(__builtin_amdgcn_exp2f)
#define EXP2F(x) __builtin_amdgcn_exp2f(x)
#else
#define EXP2F(x) exp2f(x)
#endif

#define AS1C(p) ((const __attribute__((address_space(1))) void*)(p))
#define AS3(p)  ((__attribute__((address_space(3))) void*)(p))

// ---------------------------------------------------------------------------
// Pre-kernel. Per 16-k tile (4 KB bf16): element addr = (q2*128 + c)*8 + hi*4 + j
// holding k16 = q2*4 + 8*hi + j  (q2 = lane>>5 group of the consuming wave).
// zg scaled by 1/128 here so main can atomic-add raw sums.
// Triplets: xg: (2*u0, 2*u1, -|ug|^2) 12B/g ; xt: (u0, u1, -|ut|^2, 0) 16B/t
// with u = x * sqrt(0.5*log2(e)) / ls  -> arg of exp2 is a 2-fma dot.
// ---------------------------------------------------------------------------
__global__ __launch_bounds__(256) void pre_kernel(
    const float* __restrict__ x_grid, const float* __restrict__ z_grid,
    const float* __restrict__ xt, const float* __restrict__ lsp,
    unsigned short* __restrict__ zgb, float* __restrict__ xg_trip,
    float* __restrict__ xt4)
{
  const int bid = blockIdx.x;        // 0..2047 = b*512 + t  (t = 32-k block)
  const int b   = bid >> 9;
  const int t   = bid & 511;
  const int tid = threadIdx.x;
  const int q2  = tid >> 7;
  const int c   = tid & 127;

  const size_t zbase = (size_t)b * 16384 * 128;
  const float  sc = 1.0f / 128.0f;

  #pragma unroll
  for (int h = 0; h < 2; ++h) {      // two 16-k tiles per block
    const int kb = t * 32 + h * 16 + q2 * 4;
    ushort8 v;
    #pragma unroll
    for (int hi = 0; hi < 2; ++hi)
      #pragma unroll
      for (int j = 0; j < 4; ++j) {
        float f = z_grid[zbase + (size_t)(kb + 8 * hi + j) * 128 + c] * sc;
        __bf16 hb = (__bf16)f;
        v[hi * 4 + j] = __builtin_bit_cast(unsigned short, hb);
      }
    *(ushort8*)(zgb + ((size_t)(b * 1024 + 2 * t + h)) * 2048
                    + (size_t)(q2 * 128 + c) * 8) = v;
  }

  if (tid < 64) {
    const float ls0 = 1e-5f + log1pf(expf(lsp[0]));
    const float ls1 = 1e-5f + log1pf(expf(lsp[1]));
    const float cs  = sqrtf(0.7213475204444817f);   // sqrt(0.5*log2 e)
    const float s0 = cs / ls0, s1 = cs / ls1;
    if (tid < 32) {
      const int g = t * 32 + tid;
      const float u0 = x_grid[((size_t)(b * 16384 + g)) * 2 + 0] * s0;
      const float u1 = x_grid[((size_t)(b * 16384 + g)) * 2 + 1] * s1;
      float* d = xg_trip + ((size_t)(b * 16384 + g)) * 3;
      d[0] = 2.0f * u0; d[1] = 2.0f * u1; d[2] = -(u0 * u0 + u1 * u1);
    } else if (t < 64) {
      const int r = t * 32 + (tid - 32);
      const float u0 = xt[((size_t)(b * 2048 + r)) * 2 + 0] * s0;
      const float u1 = xt[((size_t)(b * 2048 + r)) * 2 + 1] * s1;
      f32x4 d; d.x = u0; d.y = u1; d.z = -(u0 * u0 + u1 * u1); d.w = 0.0f;
      *(f32x4*)(xt4 + ((size_t)(b * 2048 + r)) * 4) = d;
    }
  }
}

// ---------------------------------------------------------------------------
// Main kernel.
// LDS ring: 3 buffers x (4 zg tiles of 4KB + 4 trip blocks of 192B pad 256)
//         = 3 x 17408 = 52224 B. Reduce phase reuses the same 48 KB.
// ---------------------------------------------------------------------------
#define BUFSTRIDE 17408
#define ZOFF(buf, kq) ((buf) * BUFSTRIDE + (kq) * 4096)
#define TOFF(buf, kq) ((buf) * BUFSTRIDE + 16384 + (kq) * 256)

__global__ __launch_bounds__(512, 2) void main_kernel(
    const unsigned short* __restrict__ zgb,
    const float* __restrict__ xg_trip,
    const float* __restrict__ xt4,
    float* __restrict__ out)
{
  __shared__ __align__(128) char smem[3 * BUFSTRIDE];

  const int bid = blockIdx.x;        // 256 = ks4 | mt16 | b4
  const int ks  = bid & 3;
  const int mt  = (bid >> 2) & 15;
  const int b   = bid >> 6;

  const int tid = threadIdx.x;
  const int wv  = tid >> 6;
  const int l   = tid & 63;
  const int kq  = wv & 3;            // contiguous K-quarter of this block
  const int rh  = wv >> 2;           // row half (64 rows each)
  const int l31 = l & 31;
  const int q2  = l >> 5;

  // xt triplets for this wave's two 32-row tiles (constant over the loop)
  float at0[2], at1[2], ca[2];
  #pragma unroll
  for (int mi = 0; mi < 2; ++mi) {
    const int r = mt * 128 + rh * 64 + mi * 32 + l31;
    f32x4 v = *(const f32x4*)(xt4 + ((size_t)(b * 2048 + r)) * 4);
    at0[mi] = v.x; at1[mi] = v.y; ca[mi] = v.z;
  }

  f32x16 acc[2][4];
  #pragma unroll
  for (int mi = 0; mi < 2; ++mi)
    #pragma unroll
    for (int ni = 0; ni < 4; ++ni)
      #pragma unroll
      for (int e = 0; e < 16; ++e)
        acc[mi][ni][e] = 0.0f;

  // this wave's 64 sequential 16-k tiles
  const char* zsrc0 = (const char*)zgb
                    + ((size_t)(b * 1024 + ks * 256 + kq * 64)) * 4096;
  const char* tsrc0 = (const char*)xg_trip
                    + ((size_t)(b * 1024 + ks * 256 + kq * 64)) * 192;

  auto stage = [&](int s) {          // 3 gl_lds per wave per stage
    const int buf = s % 3;
    const char* zs = zsrc0 + (size_t)s * 4096;
    char* zd = smem + ZOFF(buf, kq);
    __builtin_amdgcn_global_load_lds(AS1C(zs + rh * 2048 + l * 16),
                                     AS3(zd + rh * 2048 + l * 16), 16, 0, 0);
    __builtin_amdgcn_global_load_lds(AS1C(zs + rh * 2048 + 1024 + l * 16),
                                     AS3(zd + rh * 2048 + 1024 + l * 16), 16, 0, 0);
    if (l < 6) {                     // 192B of triplets, split by rh
      const char* ts = tsrc0 + (size_t)s * 192 + rh * 96;
      char* td = smem + TOFF(buf, kq) + rh * 96;
      __builtin_amdgcn_global_load_lds(AS1C(ts + l * 16),
                                       AS3(td + l * 16), 16, 0, 0);
    }
  };

  stage(0);
  stage(1);

  #pragma unroll 3
  for (int s = 0; s < 64; ++s) {
    // wait for tile s's loads; leave tile s+1's 3 loads in flight (T4)
    if (s < 63) { asm volatile("s_waitcnt vmcnt(3)" ::: "memory"); }
    else        { asm volatile("s_waitcnt vmcnt(0)" ::: "memory"); }
    __builtin_amdgcn_s_barrier();
    asm volatile("" ::: "memory");   // fence: nothing crosses the barrier

    if (s + 2 < 64) stage(s + 2);    // ring slot (s+2)%3 was last read at s-1

    const int buf = s % 3;

    // xg triplets: lane's 8 k's, broadcast reads (conflict-free)
    const float* tb = (const float*)(smem + TOFF(buf, kq) + q2 * 48);
    union { f32x4 v[3]; float f[12]; } lo, hi;
    lo.v[0] = *(const f32x4*)(tb + 0);
    lo.v[1] = *(const f32x4*)(tb + 4);
    lo.v[2] = *(const f32x4*)(tb + 8);
    hi.v[0] = *(const f32x4*)(tb + 24);
    hi.v[1] = *(const f32x4*)(tb + 28);
    hi.v[2] = *(const f32x4*)(tb + 32);

    // B-fragments: contiguous 512B per 32-lane half -> conflict-free
    const char* zt = smem + ZOFF(buf, kq) + q2 * 2048 + l31 * 16;
    short8 bfr[4];
    #pragma unroll
    for (int ni = 0; ni < 4; ++ni)
      bfr[ni] = *(const short8*)(zt + ni * 512);

    // A-fragments (RBF weights) in registers
    short8 af[2];
    #pragma unroll
    for (int mi = 0; mi < 2; ++mi) {
      union { short8 s8; __bf16 e[8]; } u;
      #pragma unroll
      for (int j = 0; j < 4; ++j) {
        float arg = __builtin_fmaf(at0[mi], lo.f[3 * j],
                    __builtin_fmaf(at1[mi], lo.f[3 * j + 1],
                                   ca[mi] + lo.f[3 * j + 2]));
        u.e[j] = (__bf16)EXP2F(arg);
      }
      #pragma unroll
      for (int j = 0; j < 4; ++j) {
        float arg = __builtin_fmaf(at0[mi], hi.f[3 * j],
                    __builtin_fmaf(at1[mi], hi.f[3 * j + 1],
                                   ca[mi] + hi.f[3 * j + 2]));
        u.e[4 + j] = (__bf16)EXP2F(arg);
      }
      af[mi] = u.s8;
    }

    #pragma unroll
    for (int mi = 0; mi < 2; ++mi)
      #pragma unroll
      for (int ni = 0; ni < 4; ++ni)
        acc[mi][ni] = __builtin_amdgcn_mfma_f32_32x32x16_bf16(
            af[mi], bfr[ni], acc[mi][ni], 0, 0, 0);
  }

  // ---- in-block reduction over the 4 K-quarters (kq==0 accumulates) ----
  // Plane layout [writer][nj][q][lane]*16B: lanes contiguous -> conflict-free.
  __syncthreads();
  float* red = (float*)smem;

  #pragma unroll
  for (int mi = 0; mi < 2; ++mi) {
    #pragma unroll
    for (int np = 0; np < 2; ++np) {
      if (kq != 0) {
        const int w = rh * 3 + (kq - 1);
        #pragma unroll
        for (int nj = 0; nj < 2; ++nj) {
          const int ni = np * 2 + nj;
          #pragma unroll
          for (int q = 0; q < 4; ++q) {
            f32x4 qv;
            qv.x = acc[mi][ni][q * 4 + 0];
            qv.y = acc[mi][ni][q * 4 + 1];
            qv.z = acc[mi][ni][q * 4 + 2];
            qv.w = acc[mi][ni][q * 4 + 3];
            *(f32x4*)(red + w * 2048 + nj * 1024 + q * 256 + l * 4) = qv;
          }
        }
      }
      __syncthreads();
      if (kq == 0) {
        #pragma unroll
        for (int nj = 0; nj < 2; ++nj) {
          const int ni = np * 2 + nj;
          #pragma unroll
          for (int src = 0; src < 3; ++src) {
            const int w = rh * 3 + src;
            #pragma unroll
            for (int q = 0; q < 4; ++q) {
              f32x4 v = *(const f32x4*)(red + w * 2048 + nj * 1024 + q * 256 + l * 4);
              acc[mi][ni][q * 4 + 0] += v.x;
              acc[mi][ni][q * 4 + 1] += v.y;
              acc[mi][ni][q * 4 + 2] += v.z;
              acc[mi][ni][q * 4 + 3] += v.w;
            }
          }
        }
      }
      __syncthreads();
    }
  }

  if (kq == 0) {                     // zg was pre-scaled by 1/128
    #pragma unroll
    for (int mi = 0; mi < 2; ++mi)
      #pragma unroll
      for (int ni = 0; ni < 4; ++ni)
        #pragma unroll
        for (int r = 0; r < 16; ++r) {
          const int row = mt * 128 + rh * 64 + mi * 32
                        + (r & 3) + 8 * (r >> 2) + 4 * q2;  // verified C/D map
          atomicAdd(out + ((size_t)b * 2048 + row) * 128 + ni * 32 + l31,
                    acc[mi][ni][r]);
        }
  }
}

// ---------------------------------------------------------------------------
extern "C" void kernel_launch(void* const* d_in, const int* in_sizes, int n_in,
                              void* d_out, int out_size, void* d_ws, size_t ws_size,
                              hipStream_t stream) {
  const float* x_grid = (const float*)d_in[0];   // (4,128,128,2)
  const float* z_grid = (const float*)d_in[1];   // (4,128,128,128)
  const float* xt     = (const float*)d_in[2];   // (4,2048,2)
  const float* lsp    = (const float*)d_in[3];   // (2,)
  float* out = (float*)d_out;                    // (4,2048,128) f32

  char* ws = (char*)d_ws;                        // ~17.7 MB used
  unsigned short* zgb = (unsigned short*)ws;                   // 16 MB
  float* xg_trip = (float*)(ws + 16777216);                    // 768 KB
  float* xt4     = (float*)(ws + 16777216 + 786432);           // 128 KB

  hipMemsetAsync(d_out, 0, (size_t)out_size * sizeof(float), stream);
  pre_kernel<<<2048, 256, 0, stream>>>(x_grid, z_grid, xt, lsp,
                                       zgb, xg_trip, xt4);
  main_kernel<<<256, 512, 0, stream>>>(zgb, xg_trip, xt4, out);
}